// Round 6
// baseline (128.193 us; speedup 1.0000x reference)
//
#include <hip/hip_runtime.h>
#include <math.h>

// GaussianCircular: separable 15x15 Gaussian conv, fp32, SAME zero-pad.
// R6 = R5 (vertical-first streaming: thread owns 4 cols, ring of 15 input
// rows, 1-row double-buffered LDS hand-off for the horizontal pass) plus a
// bank-swizzled LDS layout.
//
// R5 counter evidence: SQ_LDS_BANK_CONFLICT = 7.86M == +20 cyc on EVERY
// ds_{read,write}_b128 (16B lane stride -> each dword phase k maps lane i to
// bank (4i+k)%32: 8-way alias across lanes {i,i+8,..}). Fix: skew each
// 32-word group by 4 words: physical = w + 4*(w>>5). Our b128 bases are all
// multiples of 4 and never straddle a 32-word group, so only base addresses
// change (precomputed once per thread). Residual aliasing is 2-way = free.

#define RAD   7
#define KS    15
#define S     16               // output rows per strip
#define PRE   (2 * RAD)        // 14 prologue rows
#define PADW  8                // zero pad words each side of mid row
#define LOGW  (1024 + 2 * PADW)          // 1040 logical words
#define SW(w) ((w) + (((w) >> 5) << 2))  // group-skew swizzle
#define PHYW  1168                       // SW(1036)+4 = 1168 physical words

using f32x4 = __attribute__((ext_vector_type(4))) float;

__global__ __launch_bounds__(256) void gauss_vfirst_sw_kernel(
    const float* __restrict__ x,
    const float* __restrict__ sigma_p,
    const float* __restrict__ gain_p,
    float* __restrict__ out,
    int H, int W)
{
    __shared__ float smid[2][PHYW];          // 2 x 1168 fp32 = 9344 B

    const int strips = H / S;                // 64
    const int n      = blockIdx.x / strips;
    const int strip  = blockIdx.x - n * strips;
    const int row0   = strip * S;

    const int tid = threadIdx.x;
    const int c0  = tid * 4;                 // 256 thr * 4 = 1024 = W

    const float* __restrict__ img    = x   + (size_t)n * H * W;
    float*       __restrict__ outimg = out + (size_t)n * H * W;

    // Separable weights: gain*exp(-(i^2+j^2)/2s^2) = gain * w[i] * w[j]
    const float s    = fabsf(sigma_p[0]);
    const float gain = gain_p[0];
    const float inv  = -1.0f / (2.0f * s * s);
    float w[KS];
#pragma unroll
    for (int j = 0; j < KS; ++j) {
        const float d = (float)(j - RAD);
        w[j] = expf(d * d * inv);
    }

    // Physical LDS offsets (swizzled), hoisted out of the row loop.
    const int wb  = SW(c0 + PADW);           // write base (logical c0+8)
    const int rb0 = SW(c0 +  0);             // read window [c0, c0+20)
    const int rb1 = SW(c0 +  4);
    const int rb2 = SW(c0 +  8);
    const int rb3 = SW(c0 + 12);
    const int rb4 = SW(c0 + 16);

    // Zero the pad words once (logical [0,8) and [1032,1040), both buffers).
    // First read happens after the k=0 barrier, so no extra barrier needed.
    if (tid < PADW) {
        smid[0][SW(tid)] = 0.0f;
        smid[1][SW(tid)] = 0.0f;
        smid[0][SW(PADW + 1024 + tid)] = 0.0f;
        smid[1][SW(PADW + 1024 + tid)] = 0.0f;
    }

    // ---- prologue: input rows row0-7 .. row0+6 -> ring slots 0..13 ----
    float4 ring[15];
#pragma unroll
    for (int p = 0; p < PRE; ++p) {
        const int gr  = row0 - RAD + p;
        const int grc = max(gr, 0);                    // lower clamp
        const float m = (gr >= 0) ? 1.0f : 0.0f;
        float4 v = *(const float4*)(img + (size_t)grc * W + c0);
        v.x *= m; v.y *= m; v.z *= m; v.w *= m;
        ring[p] = v;
    }

    // ---- main: 16 output rows ----
#pragma unroll
    for (int k = 0; k < S; ++k) {
        // load input row row0+k+7 -> slot (k+14)%15 (unconditional, masked)
        {
            const int gr  = row0 + k + RAD;
            const int grc = min(gr, H - 1);            // upper clamp
            const float m = (gr < H) ? 1.0f : 0.0f;
            float4 v = *(const float4*)(img + (size_t)grc * W + c0);
            v.x *= m; v.y *= m; v.z *= m; v.w *= m;
            ring[(k + PRE) % 15] = v;
        }

        // vertical pass: mid row row0+k from ring rows -7..+7
        float4 mid = make_float4(0.f, 0.f, 0.f, 0.f);
#pragma unroll
        for (int i = 0; i < KS; ++i) {
            const float wv = w[i];
            const float4 r = ring[(k + i) % 15];       // static after unroll
            mid.x += wv * r.x; mid.y += wv * r.y;
            mid.z += wv * r.z; mid.w += wv * r.w;
        }

        const int buf = k & 1;
        float* sb = smid[buf];
        *(float4*)(sb + wb) = mid;
        __syncthreads();   // dbuf + 1 barrier/row: write(k+2) (same buf as
                           // read(k)) can't pass barrier(k+1), which is
                           // after all iter-k reads.

        // horizontal pass: 5 aligned, swizzled b128 LDS reads
        const float4 f0 = *(const float4*)(sb + rb0);
        const float4 f1 = *(const float4*)(sb + rb1);
        const float4 f2 = *(const float4*)(sb + rb2);
        const float4 f3 = *(const float4*)(sb + rb3);
        const float4 f4 = *(const float4*)(sb + rb4);
        float f[20] = { f0.x, f0.y, f0.z, f0.w,
                        f1.x, f1.y, f1.z, f1.w,
                        f2.x, f2.y, f2.z, f2.w,
                        f3.x, f3.y, f3.z, f3.w,
                        f4.x, f4.y, f4.z, f4.w };
        float4 acc = make_float4(0.f, 0.f, 0.f, 0.f);
#pragma unroll
        for (int jj = 0; jj < KS; ++jj) {
            const float wv = w[jj];
            acc.x += wv * f[1 + jj];
            acc.y += wv * f[2 + jj];
            acc.z += wv * f[3 + jj];
            acc.w += wv * f[4 + jj];
        }
        acc.x *= gain; acc.y *= gain; acc.z *= gain; acc.w *= gain;

        float* op = outimg + (size_t)(row0 + k) * W + c0;
        __builtin_nontemporal_store(*(const f32x4*)&acc, (f32x4*)op);
    }
}

extern "C" void kernel_launch(void* const* d_in, const int* in_sizes, int n_in,
                              void* d_out, int out_size, void* d_ws, size_t ws_size,
                              hipStream_t stream) {
    const float* x       = (const float*)d_in[0];
    const float* sigma_p = (const float*)d_in[1];
    const float* gain_p  = (const float*)d_in[2];
    float* out = (float*)d_out;

    const int H = 1024, W = 1024;
    const int N = in_sizes[0] / (H * W);               // 16

    const dim3 grid(N * (H / S));                      // 16 * 64 = 1024 blocks
    gauss_vfirst_sw_kernel<<<grid, 256, 0, stream>>>(x, sigma_p, gain_p, out, H, W);
}